// Round 1
// baseline (1317.294 us; speedup 1.0000x reference)
//
#include <hip/hip_runtime.h>

// out[n,c,h,w] = x[n,c,2h,2w]; x: (8,128,512,512) f32, out: (8,128,256,256) f32.
// Each thread: 2x float4 loads (8 input floats), 1x float4 store (even lanes).
__global__ __launch_bounds__(256) void strided_slice_kernel(
    const float* __restrict__ in, float* __restrict__ out) {
    // total output float4s: 8*128*256*256 / 4 = 16,777,216
    unsigned tid = blockIdx.x * blockDim.x + threadIdx.x;

    // decompose: w4 in [0,64), h in [0,256), nc in [0,1024)
    unsigned w4 = tid & 63u;          // 256/4 = 64 float4s per output row
    unsigned rem = tid >> 6;
    unsigned h = rem & 255u;
    unsigned nc = rem >> 8;

    // input row: (nc*512 + 2h) * 512 floats; within row start at 8*w4 floats
    const float4* src = reinterpret_cast<const float4*>(
        in + ((size_t)nc * 512u + 2u * h) * 512u + 8u * (size_t)w4);
    float4 a = src[0];
    float4 b = src[1];

    float4 o;
    o.x = a.x; o.y = a.z; o.z = b.x; o.w = b.z;

    float4* dst = reinterpret_cast<float4*>(out) + tid;
    *dst = o;
}

extern "C" void kernel_launch(void* const* d_in, const int* in_sizes, int n_in,
                              void* d_out, int out_size, void* d_ws, size_t ws_size,
                              hipStream_t stream) {
    const float* x = (const float*)d_in[0];
    float* out = (float*)d_out;
    // out_size = 67,108,864 -> 16,777,216 float4 threads -> 65,536 blocks of 256
    const int threads = 256;
    const int total_vec4 = out_size / 4;
    const int blocks = total_vec4 / threads;
    strided_slice_kernel<<<blocks, threads, 0, stream>>>(x, out);
}